// Round 13
// baseline (250.212 us; speedup 1.0000x reference)
//
#include <hip/hip_runtime.h>
#include <hip/hip_bf16.h>
#include <float.h>

#define B 16
#define H 32
#define HKV 8
#define G 4
#define D 128
#define LMAX 2048
#define SCALE 0.08838834764831844f  // 1/sqrt(128)

// ONE WAVE per (b, kv-head, split) [R8 structure — best measured], plus a
// FUSED split-reduce: after storing its partial, each block __threadfence()s
// and takes a ticket on cnt[b*HKV+h]; the last block LSE-merges all splits
// and writes the final output. One kernel launch total.
// part_o : [B][HKV][NSPLIT][G][D]  (written only if split non-empty)
// part_ml: [B][HKV][NSPLIT][G][2]  (m, sum_exp; always written)
// cnt    : [B*HKV] int, zeroed via hipMemsetAsync before each launch
template <int CHUNK>
__global__ __launch_bounds__(64, 3) void attn_fused(
    const float* __restrict__ q,
    const float* __restrict__ kin,
    const float* __restrict__ vin,
    const float* __restrict__ kc,
    const float* __restrict__ vc,
    const int*  __restrict__ slot_mapping,
    const int*  __restrict__ active_slots,
    const int*  __restrict__ context_lens,
    float* __restrict__ part_o,
    float* __restrict__ part_ml,
    int*   __restrict__ cnt,
    float* __restrict__ out)
{
    constexpr int NSPLIT = LMAX / CHUNK;
    const int tid   = threadIdx.x;            // 0..63
    const int split = blockIdx.x % NSPLIT;
    const int h     = (blockIdx.x / NSPLIT) % HKV;
    const int b     = blockIdx.x / (NSPLIT * HKV);

    const int ctx   = context_lens[b];
    const int start = split * CHUNK;
    int nvalid = ctx - start;
    if (nvalid > CHUNK) nvalid = CHUNK;

    const size_t pbase = ((size_t)(b * HKV + h) * NSPLIT + split) * G;

    __shared__ const float* kp[CHUNK];
    __shared__ const float* vp[CHUNK];
    __shared__ float4 sc4[CHUNK];        // scores then p
    __shared__ float wsh[32][G];         // fused-reduce weights (NSPLIT<=32)
    __shared__ float Msh[G], Lsh[G];

    if (nvalid <= 0) {
        if (tid < G * 2) part_ml[pbase * 2 + tid] = (tid & 1) ? 0.f : -FLT_MAX;
    } else {

    // ---- resolve slot -> row pointers
    for (int li = tid; li < nvalid; li += 64) {
        const int s = active_slots[b * LMAX + start + li];
        int ov = -1;
#pragma unroll
        for (int j = 0; j < 16; ++j)
            if (slot_mapping[j] == s) ov = j;
        kp[li] = (ov >= 0) ? kin + ((size_t)ov * HKV + h) * D : kc + ((size_t)s * HKV + h) * D;
        vp[li] = (ov >= 0) ? vin + ((size_t)ov * HKV + h) * D : vc + ((size_t)s * HKV + h) * D;
    }

    // ---- QK^T: 8 groups x 8 lanes; group gr owns rows it*8+gr
    const int grp   = tid >> 3;
    const int lane8 = tid & 7;

    float4 qv[G][4];   // q fragments, pre-scaled: qv[g][i] = chunk (i*8+lane8)
#pragma unroll
    for (int g = 0; g < G; ++g) {
        const float* qp = q + ((size_t)(b * H + h * G + g)) * D;
#pragma unroll
        for (int i = 0; i < 4; ++i) {
            float4 t = *(const float4*)(qp + i * 32 + lane8 * 4);
            qv[g][i] = make_float4(t.x * SCALE, t.y * SCALE, t.z * SCALE, t.w * SCALE);
        }
    }

    constexpr int KIT = CHUNK / 8;
#pragma unroll 2
    for (int it = 0; it < KIT; ++it) {
        const int r  = it * 8 + grp;
        const int rl = (r < nvalid) ? r : nvalid - 1;    // branchless clamp
        const float* kb = kp[rl];
        float pd0 = 0.f, pd1 = 0.f, pd2 = 0.f, pd3 = 0.f;
#pragma unroll
        for (int j = 0; j < 4; ++j) {
            const float4 kv = *(const float4*)(kb + j * 32 + lane8 * 4);
            pd0 += kv.x * qv[0][j].x + kv.y * qv[0][j].y + kv.z * qv[0][j].z + kv.w * qv[0][j].w;
            pd1 += kv.x * qv[1][j].x + kv.y * qv[1][j].y + kv.z * qv[1][j].z + kv.w * qv[1][j].w;
            pd2 += kv.x * qv[2][j].x + kv.y * qv[2][j].y + kv.z * qv[2][j].z + kv.w * qv[2][j].w;
            pd3 += kv.x * qv[3][j].x + kv.y * qv[3][j].y + kv.z * qv[3][j].z + kv.w * qv[3][j].w;
        }
#pragma unroll
        for (int msk = 1; msk < 8; msk <<= 1) {
            pd0 += __shfl_xor(pd0, msk, 8);
            pd1 += __shfl_xor(pd1, msk, 8);
            pd2 += __shfl_xor(pd2, msk, 8);
            pd3 += __shfl_xor(pd3, msk, 8);
        }
        if (lane8 == 0) sc4[r] = make_float4(pd0, pd1, pd2, pd3);
    }

    // ---- softmax fully in-wave: lane l owns rows {l, l+64, ...}
    {
        constexpr int SR = (CHUNK + 63) / 64;
        float4 s[SR];
#pragma unroll
        for (int k2 = 0; k2 < SR; ++k2) {
            const int l = tid + k2 * 64;
            s[k2] = sc4[l];
            if (l >= nvalid) s[k2] = make_float4(-1e30f, -1e30f, -1e30f, -1e30f);
        }
        float m0 = s[0].x, m1 = s[0].y, m2 = s[0].z, m3 = s[0].w;
#pragma unroll
        for (int k2 = 1; k2 < SR; ++k2) {
            m0 = fmaxf(m0, s[k2].x); m1 = fmaxf(m1, s[k2].y);
            m2 = fmaxf(m2, s[k2].z); m3 = fmaxf(m3, s[k2].w);
        }
#pragma unroll
        for (int msk = 1; msk < 64; msk <<= 1) {
            m0 = fmaxf(m0, __shfl_xor(m0, msk));
            m1 = fmaxf(m1, __shfl_xor(m1, msk));
            m2 = fmaxf(m2, __shfl_xor(m2, msk));
            m3 = fmaxf(m3, __shfl_xor(m3, msk));
        }
        float l0 = 0.f, l1 = 0.f, l2 = 0.f, l3 = 0.f;
#pragma unroll
        for (int k2 = 0; k2 < SR; ++k2) {
            const float4 p = make_float4(__expf(s[k2].x - m0), __expf(s[k2].y - m1),
                                         __expf(s[k2].z - m2), __expf(s[k2].w - m3));
            l0 += p.x; l1 += p.y; l2 += p.z; l3 += p.w;
            sc4[tid + k2 * 64] = p;
        }
#pragma unroll
        for (int msk = 1; msk < 64; msk <<= 1) {
            l0 += __shfl_xor(l0, msk);
            l1 += __shfl_xor(l1, msk);
            l2 += __shfl_xor(l2, msk);
            l3 += __shfl_xor(l3, msk);
        }
        if (tid == 0) {
            *(float4*)&part_ml[pbase * 2 + 0] = make_float4(m0, l0, m1, l1);
            *(float4*)&part_ml[pbase * 2 + 4] = make_float4(m2, l2, m3, l3);
        }
    }

    // ---- PV: half = row parity, 32 d-lanes x float4; p=0 kills clamped rows
    {
        const int half = tid >> 5;
        const int dl   = tid & 31;
        float4 a0 = {0,0,0,0}, a1 = {0,0,0,0}, a2 = {0,0,0,0}, a3 = {0,0,0,0};
        constexpr int VJ = CHUNK / 2;
#pragma unroll 4
        for (int j = 0; j < VJ; ++j) {
            const int r  = 2 * j + half;
            const int rl = (r < nvalid) ? r : nvalid - 1;
            const float4 vv = *(const float4*)(vp[rl] + dl * 4);
            const float4 p4 = sc4[r];
            a0.x += p4.x * vv.x; a0.y += p4.x * vv.y; a0.z += p4.x * vv.z; a0.w += p4.x * vv.w;
            a1.x += p4.y * vv.x; a1.y += p4.y * vv.y; a1.z += p4.y * vv.z; a1.w += p4.y * vv.w;
            a2.x += p4.z * vv.x; a2.y += p4.z * vv.y; a2.z += p4.z * vv.z; a2.w += p4.z * vv.w;
            a3.x += p4.w * vv.x; a3.y += p4.w * vv.y; a3.z += p4.w * vv.z; a3.w += p4.w * vv.w;
        }
#pragma unroll
        for (int c = 0; c < 4; ++c) {
            ((float*)&a0)[c] += __shfl_xor(((float*)&a0)[c], 32);
            ((float*)&a1)[c] += __shfl_xor(((float*)&a1)[c], 32);
            ((float*)&a2)[c] += __shfl_xor(((float*)&a2)[c], 32);
            ((float*)&a3)[c] += __shfl_xor(((float*)&a3)[c], 32);
        }
        if (half == 0) {
            *(float4*)(part_o + (pbase + 0) * D + dl * 4) = a0;
            *(float4*)(part_o + (pbase + 1) * D + dl * 4) = a1;
        } else {
            *(float4*)(part_o + (pbase + 2) * D + dl * 4) = a2;
            *(float4*)(part_o + (pbase + 3) * D + dl * 4) = a3;
        }
    }
    }  // nvalid > 0

    // ---- fused split-reduce: last block per (b,h) merges all splits
    __threadfence();                       // make partials device-visible
    int tk = 0;
    if (tid == 0) tk = atomicAdd(&cnt[b * HKV + h], 1);
    tk = __shfl(tk, 0);
    if (tk != NSPLIT - 1) return;
    __threadfence();                       // acquire: see others' partials

    const size_t base = (size_t)(b * HKV + h) * NSPLIT;

    // weights: lane g<4 computes M,L serially (NSPLIT<=32 -> cheap)
    if (tid < G) {
        const int g = tid;
        float Mg = -FLT_MAX;
        for (int s = 0; s < NSPLIT; ++s) {
            const float l = part_ml[((base + s) * G + g) * 2 + 1];
            if (l > 0.f) Mg = fmaxf(Mg, part_ml[((base + s) * G + g) * 2 + 0]);
        }
        float Lg = 0.f;
        for (int s = 0; s < NSPLIT; ++s) {
            const float l = part_ml[((base + s) * G + g) * 2 + 1];
            const float w = (l > 0.f) ? __expf(part_ml[((base + s) * G + g) * 2 + 0] - Mg) : 0.f;
            wsh[s][g] = w;
            Lg += l * w;
        }
        Msh[g] = Mg;
        Lsh[g] = (Lg > 0.f) ? Lg : 1.f;
    }
    __syncthreads();   // single wave: ordering only

    // outputs: G*D = 512 values, 8 per thread
#pragma unroll
    for (int o = 0; o < 8; ++o) {
        const int idx = tid + o * 64;       // [G][D] flat
        const int g = idx >> 7, d = idx & 127;
        float acc = 0.f;
        for (int s = 0; s < NSPLIT; ++s) {
            const float w = wsh[s][g];
            if (w > 0.f) acc += w * part_o[((base + s) * G + g) * D + d];
        }
        out[((size_t)(b * H) + h * G + g) * D + d] = acc / Lsh[g];
    }
}

extern "C" void kernel_launch(void* const* d_in, const int* in_sizes, int n_in,
                              void* d_out, int out_size, void* d_ws, size_t ws_size,
                              hipStream_t stream) {
    const float* q  = (const float*)d_in[0];
    const float* k  = (const float*)d_in[1];
    const float* v  = (const float*)d_in[2];
    const float* kc = (const float*)d_in[3];
    const float* vc = (const float*)d_in[4];
    const int* slot_mapping = (const int*)d_in[5];
    const int* active_slots = (const int*)d_in[6];
    const int* context_lens = (const int*)d_in[7];
    float* out = (float*)d_out;

    const size_t perSplit = (size_t)B * HKV * (G * D + G * 2) * sizeof(float);
    const size_t cntBytes = (size_t)B * HKV * sizeof(int);
    int nsplit = 8;
    if (ws_size >= 32 * perSplit + cntBytes)      nsplit = 32;
    else if (ws_size >= 16 * perSplit + cntBytes) nsplit = 16;

    float* part_o  = (float*)d_ws;
    float* part_ml = part_o + (size_t)B * HKV * nsplit * G * D;
    int*   cnt     = (int*)(part_ml + (size_t)B * HKV * nsplit * G * 2);

    hipMemsetAsync(cnt, 0, cntBytes, stream);

    if (nsplit == 32) {
        attn_fused<64><<<B * HKV * 32, 64, 0, stream>>>(
            q, k, v, kc, vc, slot_mapping, active_slots, context_lens,
            part_o, part_ml, cnt, out);
    } else if (nsplit == 16) {
        attn_fused<128><<<B * HKV * 16, 64, 0, stream>>>(
            q, k, v, kc, vc, slot_mapping, active_slots, context_lens,
            part_o, part_ml, cnt, out);
    } else {
        attn_fused<256><<<B * HKV * 8, 64, 0, stream>>>(
            q, k, v, kc, vc, slot_mapping, active_slots, context_lens,
            part_o, part_ml, cnt, out);
    }
}

// Round 14
// 41.846 us; speedup vs baseline: 5.9794x; 5.9794x over previous
//
#include <hip/hip_runtime.h>
#include <hip/hip_bf16.h>
#include <float.h>

#define B 16
#define H 32
#define HKV 8
#define G 4
#define D 128
#define LMAX 2048
#define SCALE 0.08838834764831844f  // 1/sqrt(128)

// Kernel 1: ONE WAVE per (b, kv-head, split). No barriers, no inter-wave
// coupling: the wave resolves its chunk's slot pointers, computes QK^T
// (8-lane groups per row), does softmax entirely in-wave (row l owned by
// lane l), then PV (2 row-halves x 32 d-lanes), and stores the partial.
// Invalid rows are handled branchlessly: loads clamp to row nvalid-1 and
// their p is forced to 0, so they contribute nothing.
// Best-measured configuration (41.8 us); fusion/granule/occupancy variants
// all measured neutral-to-worse (rounds 4-13).
// part_o : [B][HKV][NSPLIT][G][D]  (written only if split non-empty)
// part_ml: [B][HKV][NSPLIT][G][2]  (m, sum_exp; always written)
template <int CHUNK>
__global__ __launch_bounds__(64, 3) void attn_partial(
    const float* __restrict__ q,
    const float* __restrict__ kin,
    const float* __restrict__ vin,
    const float* __restrict__ kc,
    const float* __restrict__ vc,
    const int*  __restrict__ slot_mapping,
    const int*  __restrict__ active_slots,
    const int*  __restrict__ context_lens,
    float* __restrict__ part_o,
    float* __restrict__ part_ml)
{
    constexpr int NSPLIT = LMAX / CHUNK;
    const int tid   = threadIdx.x;            // 0..63
    const int split = blockIdx.x % NSPLIT;
    const int h     = (blockIdx.x / NSPLIT) % HKV;
    const int b     = blockIdx.x / (NSPLIT * HKV);

    const int ctx   = context_lens[b];
    const int start = split * CHUNK;
    int nvalid = ctx - start;
    if (nvalid > CHUNK) nvalid = CHUNK;

    const size_t pbase = ((size_t)(b * HKV + h) * NSPLIT + split) * G;

    if (nvalid <= 0) {
        if (tid < G * 2) part_ml[pbase * 2 + tid] = (tid & 1) ? 0.f : -FLT_MAX;
        return;
    }

    __shared__ const float* kp[CHUNK];   // wave-private (1 wave per block)
    __shared__ const float* vp[CHUNK];
    __shared__ float4 sc4[CHUNK];        // scores then p, one float4 (4 heads) per row

    // ---- resolve slot -> row pointers (uniform slot_mapping -> scalar loads)
    for (int li = tid; li < nvalid; li += 64) {
        const int s = active_slots[b * LMAX + start + li];
        int ov = -1;
#pragma unroll
        for (int j = 0; j < 16; ++j)
            if (slot_mapping[j] == s) ov = j;
        kp[li] = (ov >= 0) ? kin + ((size_t)ov * HKV + h) * D : kc + ((size_t)s * HKV + h) * D;
        vp[li] = (ov >= 0) ? vin + ((size_t)ov * HKV + h) * D : vc + ((size_t)s * HKV + h) * D;
    }

    // ---- QK^T: 8 groups x 8 lanes; group gr owns rows it*8+gr
    const int grp   = tid >> 3;
    const int lane8 = tid & 7;

    float4 qv[G][4];   // q fragments, pre-scaled: qv[g][i] = chunk (i*8+lane8)
#pragma unroll
    for (int g = 0; g < G; ++g) {
        const float* qp = q + ((size_t)(b * H + h * G + g)) * D;
#pragma unroll
        for (int i = 0; i < 4; ++i) {
            float4 t = *(const float4*)(qp + i * 32 + lane8 * 4);
            qv[g][i] = make_float4(t.x * SCALE, t.y * SCALE, t.z * SCALE, t.w * SCALE);
        }
    }

    constexpr int KIT = CHUNK / 8;
#pragma unroll 2
    for (int it = 0; it < KIT; ++it) {
        const int r  = it * 8 + grp;
        const int rl = (r < nvalid) ? r : nvalid - 1;    // branchless clamp
        const float* kb = kp[rl];
        float pd0 = 0.f, pd1 = 0.f, pd2 = 0.f, pd3 = 0.f;
#pragma unroll
        for (int j = 0; j < 4; ++j) {
            const float4 kv = *(const float4*)(kb + j * 32 + lane8 * 4);
            pd0 += kv.x * qv[0][j].x + kv.y * qv[0][j].y + kv.z * qv[0][j].z + kv.w * qv[0][j].w;
            pd1 += kv.x * qv[1][j].x + kv.y * qv[1][j].y + kv.z * qv[1][j].z + kv.w * qv[1][j].w;
            pd2 += kv.x * qv[2][j].x + kv.y * qv[2][j].y + kv.z * qv[2][j].z + kv.w * qv[2][j].w;
            pd3 += kv.x * qv[3][j].x + kv.y * qv[3][j].y + kv.z * qv[3][j].z + kv.w * qv[3][j].w;
        }
#pragma unroll
        for (int msk = 1; msk < 8; msk <<= 1) {
            pd0 += __shfl_xor(pd0, msk, 8);
            pd1 += __shfl_xor(pd1, msk, 8);
            pd2 += __shfl_xor(pd2, msk, 8);
            pd3 += __shfl_xor(pd3, msk, 8);
        }
        if (lane8 == 0) sc4[r] = make_float4(pd0, pd1, pd2, pd3);
    }

    // ---- softmax fully in-wave: lane l owns rows {l, l+64, ...}
    {
        constexpr int SR = (CHUNK + 63) / 64;
        float4 s[SR];
#pragma unroll
        for (int k2 = 0; k2 < SR; ++k2) {
            const int l = tid + k2 * 64;
            s[k2] = sc4[l];
            if (l >= nvalid) s[k2] = make_float4(-1e30f, -1e30f, -1e30f, -1e30f);
        }
        float m0 = s[0].x, m1 = s[0].y, m2 = s[0].z, m3 = s[0].w;
#pragma unroll
        for (int k2 = 1; k2 < SR; ++k2) {
            m0 = fmaxf(m0, s[k2].x); m1 = fmaxf(m1, s[k2].y);
            m2 = fmaxf(m2, s[k2].z); m3 = fmaxf(m3, s[k2].w);
        }
#pragma unroll
        for (int msk = 1; msk < 64; msk <<= 1) {
            m0 = fmaxf(m0, __shfl_xor(m0, msk));
            m1 = fmaxf(m1, __shfl_xor(m1, msk));
            m2 = fmaxf(m2, __shfl_xor(m2, msk));
            m3 = fmaxf(m3, __shfl_xor(m3, msk));
        }
        float l0 = 0.f, l1 = 0.f, l2 = 0.f, l3 = 0.f;
#pragma unroll
        for (int k2 = 0; k2 < SR; ++k2) {
            const float4 p = make_float4(__expf(s[k2].x - m0), __expf(s[k2].y - m1),
                                         __expf(s[k2].z - m2), __expf(s[k2].w - m3));
            l0 += p.x; l1 += p.y; l2 += p.z; l3 += p.w;
            sc4[tid + k2 * 64] = p;
        }
#pragma unroll
        for (int msk = 1; msk < 64; msk <<= 1) {
            l0 += __shfl_xor(l0, msk);
            l1 += __shfl_xor(l1, msk);
            l2 += __shfl_xor(l2, msk);
            l3 += __shfl_xor(l3, msk);
        }
        if (tid == 0) {
            *(float4*)&part_ml[pbase * 2 + 0] = make_float4(m0, l0, m1, l1);
            *(float4*)&part_ml[pbase * 2 + 4] = make_float4(m2, l2, m3, l3);
        }
    }

    // ---- PV: half = row parity, 32 d-lanes x float4; p=0 kills clamped rows
    {
        const int half = tid >> 5;
        const int dl   = tid & 31;
        float4 a0 = {0,0,0,0}, a1 = {0,0,0,0}, a2 = {0,0,0,0}, a3 = {0,0,0,0};
        constexpr int VJ = CHUNK / 2;
#pragma unroll 4
        for (int j = 0; j < VJ; ++j) {
            const int r  = 2 * j + half;
            const int rl = (r < nvalid) ? r : nvalid - 1;
            const float4 vv = *(const float4*)(vp[rl] + dl * 4);
            const float4 p4 = sc4[r];
            a0.x += p4.x * vv.x; a0.y += p4.x * vv.y; a0.z += p4.x * vv.z; a0.w += p4.x * vv.w;
            a1.x += p4.y * vv.x; a1.y += p4.y * vv.y; a1.z += p4.y * vv.z; a1.w += p4.y * vv.w;
            a2.x += p4.z * vv.x; a2.y += p4.z * vv.y; a2.z += p4.z * vv.z; a2.w += p4.z * vv.w;
            a3.x += p4.w * vv.x; a3.y += p4.w * vv.y; a3.z += p4.w * vv.z; a3.w += p4.w * vv.w;
        }
        // combine the two row-parities: xor-32 shuffle (both halves end full)
#pragma unroll
        for (int c = 0; c < 4; ++c) {
            ((float*)&a0)[c] += __shfl_xor(((float*)&a0)[c], 32);
            ((float*)&a1)[c] += __shfl_xor(((float*)&a1)[c], 32);
            ((float*)&a2)[c] += __shfl_xor(((float*)&a2)[c], 32);
            ((float*)&a3)[c] += __shfl_xor(((float*)&a3)[c], 32);
        }
        if (half == 0) {
            *(float4*)(part_o + (pbase + 0) * D + dl * 4) = a0;
            *(float4*)(part_o + (pbase + 1) * D + dl * 4) = a1;
        } else {
            *(float4*)(part_o + (pbase + 2) * D + dl * 4) = a2;
            *(float4*)(part_o + (pbase + 3) * D + dl * 4) = a3;
        }
    }
}

// Kernel 2: merge nsplit partials per (b, h, g) with log-sum-exp combine.
__global__ __launch_bounds__(128) void attn_reduce(
    const float* __restrict__ part_o,
    const float* __restrict__ part_ml,
    float* __restrict__ out,
    int nsplit)
{
    const int g = blockIdx.x & 3;
    const int h = (blockIdx.x >> 2) & 7;
    const int b = blockIdx.x >> 5;
    const int d = threadIdx.x;

    __shared__ float mlds[32], llds[32];
    const size_t base = (size_t)(b * HKV + h) * nsplit;

    for (int s = d; s < nsplit; s += 128) {
        mlds[s] = part_ml[((base + s) * G + g) * 2 + 0];
        llds[s] = part_ml[((base + s) * G + g) * 2 + 1];
    }
    __syncthreads();

    float M = -FLT_MAX;
    for (int s = 0; s < nsplit; ++s)
        if (llds[s] > 0.f) M = fmaxf(M, mlds[s]);

    float L = 0.f, acc = 0.f;
    for (int s = 0; s < nsplit; ++s) {
        const float l = llds[s];
        if (l > 0.f) {
            const float e = __expf(mlds[s] - M);
            L += l * e;
            acc += e * part_o[((base + s) * G + g) * D + d];
        }
    }
    out[((size_t)(b * H) + h * G + g) * D + d] = acc / (L > 0.f ? L : 1.f);
}

extern "C" void kernel_launch(void* const* d_in, const int* in_sizes, int n_in,
                              void* d_out, int out_size, void* d_ws, size_t ws_size,
                              hipStream_t stream) {
    const float* q  = (const float*)d_in[0];
    const float* k  = (const float*)d_in[1];
    const float* v  = (const float*)d_in[2];
    const float* kc = (const float*)d_in[3];
    const float* vc = (const float*)d_in[4];
    const int* slot_mapping = (const int*)d_in[5];
    const int* active_slots = (const int*)d_in[6];
    const int* context_lens = (const int*)d_in[7];
    float* out = (float*)d_out;

    const size_t perSplit = (size_t)B * HKV * (G * D + G * 2) * sizeof(float);
    int nsplit = 8;
    if (ws_size >= 32 * perSplit)      nsplit = 32;
    else if (ws_size >= 16 * perSplit) nsplit = 16;

    float* part_o  = (float*)d_ws;
    float* part_ml = part_o + (size_t)B * HKV * nsplit * G * D;

    if (nsplit == 32) {
        attn_partial<64><<<B * HKV * 32, 64, 0, stream>>>(
            q, k, v, kc, vc, slot_mapping, active_slots, context_lens, part_o, part_ml);
    } else if (nsplit == 16) {
        attn_partial<128><<<B * HKV * 16, 64, 0, stream>>>(
            q, k, v, kc, vc, slot_mapping, active_slots, context_lens, part_o, part_ml);
    } else {
        attn_partial<256><<<B * HKV * 8, 64, 0, stream>>>(
            q, k, v, kc, vc, slot_mapping, active_slots, context_lens, part_o, part_ml);
    }
    attn_reduce<<<B * HKV * G, 128, 0, stream>>>(part_o, part_ml, out, nsplit);
}